// Round 1
// baseline (402.419 us; speedup 1.0000x reference)
//
#include <hip/hip_runtime.h>

// EMASlopeFilter: x (64,4096,64) fp32 -> (ema, slope, above, below, between), each (64,4096,64) fp32.
// Sequential EMA recurrence along T per (b,f) series; chunked with zero-carry warmup
// (omega^256 ~ 1.3e-9 => warmup error negligible; chunks 0/1 start at t=0 and are exact,
// which covers the entire early transient where |ema| reaches ~8e5 and signals flip).

constexpr int kB  = 64;
constexpr int kT  = 4096;
constexpr int kF  = 64;
constexpr int kNC = 16;          // chunks along T
constexpr int kC  = kT / kNC;    // 256 output steps per chunk
constexpr int kW  = 256;         // warmup steps (zero-carry start)
constexpr int kLag = 25;
constexpr float kUpper = 15.0f;
constexpr float kLower = -15.0f;
constexpr size_t kN = (size_t)kB * kT * kF;   // 16777216 elements per output tensor

__global__ __launch_bounds__(256)
void ema_slope_kernel(const float* __restrict__ x, float* __restrict__ out) {
    const float kAlpha = (float)(2.0 / 26.0);
    const float kOm    = 1.0f - kAlpha;

    __shared__ float s_w[256];            // adjust weights, t in [0,256); w==1.0f beyond
    __shared__ float s_ring[256 * kLag];  // per-thread 25-deep ema ring (stride 25: 2-way banks, free)

    // Build w table: s_w[t] = max(1 - om^(t+1), 1e-10). Double accumulation ~= correctly
    // rounded f32 (matches host powf to <=1 ulp in practice).
    {
        const int t = threadIdx.x;
        const double omd = (double)kOm;
        double p = 1.0;
        for (int i = 0; i <= t; ++i) p *= omd;   // om^(t+1)
        s_w[t] = fmaxf(1.0f - (float)p, 1e-10f);
    }
    __syncthreads();

    const int lane  = threadIdx.x & 63;        // f
    const int wv    = threadIdx.x >> 6;        // wave in block
    const int chunk = blockIdx.x & (kNC - 1);  // all waves of a block share chunk
    const int b     = (blockIdx.x >> 4) * 4 + wv;

    const int t_out0 = chunk * kC;             // first output t
    const int t_end  = t_out0 + kC;            // exclusive
    const int tl0    = t_end - (kC + kW);      // 512-iteration window start (may be <0 for chunk 0)

    const float* xb = x   + (size_t)b * kT * kF + lane;
    float*       o0 = out + (size_t)b * kT * kF + lane;   // ema; others at +kN..+4kN

    float* ring = &s_ring[(size_t)threadIdx.x * kLag];

    float c;
    if (tl0 <= 0) {
        // chunks 0 and 1 start the recurrence exactly at t=0: ema0 = x0 (no adjust)
        c = xb[0];
        ring[0] = c;
        if (chunk == 0) {
            float slope = c;                       // lagged = 0 for t < 25
            o0[0]      = c;
            o0[kN]     = slope;
            o0[2 * kN] = (slope > kUpper) ? 1.0f : 0.0f;
            o0[3 * kN] = (slope < kLower) ? 1.0f : 0.0f;
            o0[4 * kN] = (slope >= kLower && slope <= kUpper) ? 1.0f : 0.0f;
        }
    } else {
        c = 0.0f;  // zero-carry warmup start; error ~ |c_true| * om^256 ~ 1e-9
    }

    constexpr int G = 16;                       // load-pipeline depth (static register buffer)
    float xpre[G];
#pragma unroll
    for (int j = 0; j < G; ++j) {
        int tj = tl0 + j;
        float v = 0.0f;
        if (tj >= 0) v = xb[(size_t)tj * kF];
        xpre[j] = v;
    }

    const int ngroups = (kC + kW) / G;          // 32
    for (int g = 0; g < ngroups; ++g) {
        const int tg = tl0 + g * G;
        float xnext[G];
        if (g + 1 < ngroups) {
#pragma unroll
            for (int j = 0; j < G; ++j) {
                int tj = tg + G + j;
                float v = 0.0f;
                if (tj >= 0) v = xb[(size_t)tj * kF];
                xnext[j] = v;
            }
        }
#pragma unroll
        for (int j = 0; j < G; ++j) {
            const int tj = tg + j;
            if (tj >= 1) {
                // Mirror reference fp32 op order exactly (no FMA contraction):
                // e = alpha*x + om*c; c = e / max(1-om^(t+1),1e-10)  [w==1.0f for t>=256]
                float e = __fadd_rn(__fmul_rn(kAlpha, xpre[j]), __fmul_rn(kOm, c));
                c = (tj < 256) ? __fdiv_rn(e, s_w[tj]) : e;

                const int slot = (unsigned)tj % (unsigned)kLag;
                float lagv = ring[slot];        // ema[t-25] (written 25 steps ago)
                ring[slot] = c;

                if (tj >= t_out0) {
                    float slope = (tj >= kLag) ? __fsub_rn(c, lagv) : c;
                    size_t off = (size_t)tj * kF;
                    o0[off]          = c;
                    o0[off + kN]     = slope;
                    o0[off + 2 * kN] = (slope > kUpper) ? 1.0f : 0.0f;
                    o0[off + 3 * kN] = (slope < kLower) ? 1.0f : 0.0f;
                    o0[off + 4 * kN] = (slope >= kLower && slope <= kUpper) ? 1.0f : 0.0f;
                }
            }
        }
        if (g + 1 < ngroups) {
#pragma unroll
            for (int j = 0; j < G; ++j) xpre[j] = xnext[j];
        }
    }
}

extern "C" void kernel_launch(void* const* d_in, const int* in_sizes, int n_in,
                              void* d_out, int out_size, void* d_ws, size_t ws_size,
                              hipStream_t stream) {
    const float* x = (const float*)d_in[0];
    float* out = (float*)d_out;
    // 256 blocks x 256 threads: block = 4 waves (4 b-values) sharing one chunk;
    // 64 b x 16 chunks = 1024 waves total (4 waves/CU).
    dim3 grid(kB / 4 * kNC);
    dim3 block(256);
    ema_slope_kernel<<<grid, block, 0, stream>>>(x, out);
}